// Round 5
// baseline (915.442 us; speedup 1.0000x reference)
//
#include <hip/hip_runtime.h>
#include <stdint.h>

#define NB 64
#define DD 256
#define HH 512
#define NGROUP 2048

typedef __attribute__((ext_vector_type(8))) _Float16 half8;
typedef __attribute__((ext_vector_type(4))) float f32x4;

__device__ __forceinline__ half8 ld8(const _Float16* p) {
    return *reinterpret_cast<const half8*>(p);
}

// ---------------- precompute kernels (validated R1-R4) ----------------

__global__ void prep_G_kernel(const float* __restrict__ Wq, const float* __restrict__ Wk,
                              _Float16* __restrict__ G, float scale) {
    const int d = blockIdx.x;
    const int e = threadIdx.x;
    const float4* qa = reinterpret_cast<const float4*>(Wq + d * HH);
    const float4* ka = reinterpret_cast<const float4*>(Wk + e * HH);
    float s = 0.f;
    #pragma unroll 8
    for (int j = 0; j < HH / 4; ++j) {
        float4 a = qa[j], b = ka[j];
        s += a.x * b.x + a.y * b.y + a.z * b.z + a.w * b.w;
    }
    G[d * DD + e] = (_Float16)(s * scale);
}

__global__ void prep_U_kernel(const float* __restrict__ Wv, const float* __restrict__ W1p,
                              _Float16* __restrict__ UT, int coff) {
    const int o = blockIdx.x;
    const int d = threadIdx.x;
    const float4* va = reinterpret_cast<const float4*>(Wv + d * HH);
    float s = 0.f;
    #pragma unroll 4
    for (int j4 = 0; j4 < HH / 4; ++j4) {
        float4 a = va[j4];
        const int j = j4 * 4;
        s += a.x * W1p[(j + 0) * HH + o];
        s += a.y * W1p[(j + 1) * HH + o];
        s += a.z * W1p[(j + 2) * HH + o];
        s += a.w * W1p[(j + 3) * HH + o];
    }
    UT[o * HH + coff + d] = (_Float16)s;
}

__global__ void prep_W2T_kernel(const float* __restrict__ W2, _Float16* __restrict__ W2T) {
    __shared__ float tile[32][33];
    const int bk = blockIdx.x * 32;
    const int bh = blockIdx.y * 32;
    const int tx = threadIdx.x & 31, ty = threadIdx.x >> 5;
    #pragma unroll
    for (int i = 0; i < 32; i += 8)
        tile[ty + i][tx] = W2[(bh + ty + i) * HH + bk + tx];
    __syncthreads();
    #pragma unroll
    for (int i = 0; i < 32; i += 8)
        W2T[(bk + ty + i) * HH + bh + tx] = (_Float16)tile[tx][ty + i];
}

// ---------------- main fused kernel ----------------
// LDS 80 KiB -> 2 blocks/CU:
//   X1 @ 0      [64][256] f16 swz -> becomes g1
//   X2 @ 32768  [64][256] f16 swz -> becomes g2
//   R  @ 65536  16 KiB multiplexed:
//     scores: A-chunk [64][128] (full 16K)
//     PV:     P [64][64] @R, XT [64][64] @R+8K
//     MLP:    h-chunk [64][64] dbuf @R / @R+8K
// swizzle: byte ^= (row&7)<<4

#define RBASE 65536
__device__ __forceinline__ int axX(int side, int row, int ec) {   // 512B rows
    return side * 32768 + row * 512 + ((2 * ec) ^ ((row & 7) << 4));
}
__device__ __forceinline__ int axA(int row, int ec) {             // 256B rows (A-chunk)
    return RBASE + row * 256 + ((2 * ec) ^ ((row & 7) << 4));
}
__device__ __forceinline__ int axP(int row, int ec) {             // 128B rows (P)
    return RBASE + row * 128 + ((2 * ec) ^ ((row & 7) << 4));
}
__device__ __forceinline__ int axT(int row, int ec) {             // 128B rows (XT)
    return RBASE + 8192 + row * 128 + ((2 * ec) ^ ((row & 7) << 4));
}
__device__ __forceinline__ int axH(int base, int row, int ec) {   // 128B rows (h dbuf)
    return base + row * 128 + ((2 * ec) ^ ((row & 7) << 4));
}

__global__ __launch_bounds__(512, 4)
void fused_kernel(const float* __restrict__ x1g, const float* __restrict__ x2g,
                  const _Float16* __restrict__ G1, const _Float16* __restrict__ G2,
                  const _Float16* __restrict__ UT, const _Float16* __restrict__ W2T,
                  const float* __restrict__ b1, const float* __restrict__ b2,
                  float* __restrict__ out) {
    __shared__ __align__(16) char lds[81920];

    const int tid = threadIdx.x;
    const int lane = tid & 63;
    const int w = tid >> 6;
    const int c = lane & 15;
    const int kg = lane >> 4;
    const size_t g = blockIdx.x;
    const f32x4 z = {0.f, 0.f, 0.f, 0.f};

    // ---- Phase 0: stage x -> f16 swizzled LDS ----
    {
        const float4* s1 = reinterpret_cast<const float4*>(x1g) + g * (NB * DD / 4);
        const float4* s2 = reinterpret_cast<const float4*>(x2g) + g * (NB * DD / 4);
        #pragma unroll
        for (int it = 0; it < 4; ++it) {
            const int G_ = tid + 512 * it;
            const int row = G_ >> 5, cg = G_ & 31;
            float4 a0 = s1[row * 64 + cg * 2], a1 = s1[row * 64 + cg * 2 + 1];
            float4 b0 = s2[row * 64 + cg * 2], b1v = s2[row * 64 + cg * 2 + 1];
            half8 ha, hb;
            ha[0] = (_Float16)a0.x; ha[1] = (_Float16)a0.y; ha[2] = (_Float16)a0.z; ha[3] = (_Float16)a0.w;
            ha[4] = (_Float16)a1.x; ha[5] = (_Float16)a1.y; ha[6] = (_Float16)a1.z; ha[7] = (_Float16)a1.w;
            hb[0] = (_Float16)b0.x; hb[1] = (_Float16)b0.y; hb[2] = (_Float16)b0.z; hb[3] = (_Float16)b0.w;
            hb[4] = (_Float16)b1v.x; hb[5] = (_Float16)b1v.y; hb[6] = (_Float16)b1v.z; hb[7] = (_Float16)b1v.w;
            *reinterpret_cast<half8*>(lds + axX(0, row, cg * 8)) = ha;
            *reinterpret_cast<half8*>(lds + axX(1, row, cg * 8)) = hb;
        }
    }
    __syncthreads();

    // ---- Scores (coarse, R3): 128-col A-chunks; S1 in waves 0-3, S2 in 4-7 ----
    f32x4 Sacc[4] = {z, z, z, z};
    const int wn = w & 3;
    const int ar2 = w >> 2;
    #pragma unroll
    for (int ai = 0; ai < 2; ++ai) {
        const _Float16* Gm = ai ? G2 : G1;
        const int xsrc = ai ? 0 : 1;   // A2 = X2@G1^T ; A1 = X1@G2^T
        const int xq   = ai ? 1 : 0;   // S1 = X1@A2^T ; S2 = X2@A1^T
        #pragma unroll
        for (int ci = 0; ci < 2; ++ci) {
            const _Float16* gp = Gm + (size_t)(128 * ci + 16 * w + c) * DD;
            half8 bf[8];
            #pragma unroll
            for (int ks = 0; ks < 8; ++ks) bf[ks] = ld8(gp + 32 * ks + 8 * kg);
            #pragma unroll
            for (int i = 0; i < 4; ++i) {
                f32x4 acc = z;
                #pragma unroll
                for (int ks = 0; ks < 8; ++ks) {
                    half8 af = *reinterpret_cast<const half8*>(lds + axX(xsrc, 16 * i + c, 32 * ks + 8 * kg));
                    acc = __builtin_amdgcn_mfma_f32_16x16x32_f16(af, bf[ks], acc, 0, 0, 0);
                }
                #pragma unroll
                for (int r = 0; r < 4; ++r)
                    *reinterpret_cast<_Float16*>(lds + axA(16 * i + 4 * kg + r, 16 * w + c)) = (_Float16)acc[r];
            }
            __syncthreads();
            if (ar2 == ai) {
                #pragma unroll
                for (int ks = 0; ks < 4; ++ks) {
                    half8 af = *reinterpret_cast<const half8*>(lds + axX(xq, 16 * wn + c, 128 * ci + 32 * ks + 8 * kg));
                    #pragma unroll
                    for (int j = 0; j < 4; ++j) {
                        half8 bfr = *reinterpret_cast<const half8*>(lds + axA(16 * j + c, 32 * ks + 8 * kg));
                        Sacc[j] = __builtin_amdgcn_mfma_f32_16x16x32_f16(af, bfr, Sacc[j], 0, 0, 0);
                    }
                }
            }
            __syncthreads();
        }
    }

    // ---- Per side: softmax -> P; PV via XT tile (conflict-free writes) -> g over X ----
    #pragma unroll
    for (int s = 0; s < 2; ++s) {
        if (ar2 == s) {
            #pragma unroll
            for (int r = 0; r < 4; ++r) {
                float m0 = fmaxf(fmaxf(Sacc[0][r], Sacc[1][r]), fmaxf(Sacc[2][r], Sacc[3][r]));
                m0 = fmaxf(m0, __shfl_xor(m0, 1));
                m0 = fmaxf(m0, __shfl_xor(m0, 2));
                m0 = fmaxf(m0, __shfl_xor(m0, 4));
                m0 = fmaxf(m0, __shfl_xor(m0, 8));
                float e0 = __expf(Sacc[0][r] - m0);
                float e1 = __expf(Sacc[1][r] - m0);
                float e2 = __expf(Sacc[2][r] - m0);
                float e3 = __expf(Sacc[3][r] - m0);
                float s0 = e0 + e1 + e2 + e3;
                s0 += __shfl_xor(s0, 1);
                s0 += __shfl_xor(s0, 2);
                s0 += __shfl_xor(s0, 4);
                s0 += __shfl_xor(s0, 8);
                const float inv = 1.f / s0;
                const int row = 16 * wn + 4 * kg + r;
                *reinterpret_cast<_Float16*>(lds + axP(row, 16 * 0 + c)) = (_Float16)(e0 * inv);
                *reinterpret_cast<_Float16*>(lds + axP(row, 16 * 1 + c)) = (_Float16)(e1 * inv);
                *reinterpret_cast<_Float16*>(lds + axP(row, 16 * 2 + c)) = (_Float16)(e2 * inv);
                *reinterpret_cast<_Float16*>(lds + axP(row, 16 * 3 + c)) = (_Float16)(e3 * inv);
            }
        }
        __syncthreads();

        const int wr = w & 3, wc = w >> 2;
        // P A-fragments (rows 16wr..16wr+15, k = m 0..63)
        half8 paf0 = *reinterpret_cast<const half8*>(lds + axP(16 * wr + c, 8 * kg));
        half8 paf1 = *reinterpret_cast<const half8*>(lds + axP(16 * wr + c, 32 + 8 * kg));

        #pragma unroll
        for (int ci = 0; ci < 4; ++ci) {
            // transpose 64-col X slice -> XT[d-local][m]; writes conflict-free (row uniform)
            half8 v = *reinterpret_cast<const half8*>(lds + axX(s, lane, 64 * ci + 8 * w));
            #pragma unroll
            for (int e = 0; e < 8; ++e)
                *reinterpret_cast<_Float16*>(lds + axT(8 * w + e, lane)) = v[e];
            __syncthreads();
            // g tile: wave (wr, wc): rows 16wr.., d-cols 32wc.. within chunk
            f32x4 acc0 = z, acc1 = z;
            #pragma unroll
            for (int ks = 0; ks < 2; ++ks) {
                half8 pa = ks ? paf1 : paf0;
                half8 b0 = *reinterpret_cast<const half8*>(lds + axT(32 * wc + c, 32 * ks + 8 * kg));
                half8 b1f = *reinterpret_cast<const half8*>(lds + axT(32 * wc + 16 + c, 32 * ks + 8 * kg));
                acc0 = __builtin_amdgcn_mfma_f32_16x16x32_f16(pa, b0, acc0, 0, 0, 0);
                acc1 = __builtin_amdgcn_mfma_f32_16x16x32_f16(pa, b1f, acc1, 0, 0, 0);
            }
            #pragma unroll
            for (int r = 0; r < 4; ++r) {
                *reinterpret_cast<_Float16*>(lds + axX(s, 16 * wr + 4 * kg + r, 64 * ci + 32 * wc + c)) = (_Float16)acc0[r];
                *reinterpret_cast<_Float16*>(lds + axX(s, 16 * wr + 4 * kg + r, 64 * ci + 32 * wc + 16 + c)) = (_Float16)acc1[r];
            }
            __syncthreads();
        }
    }

    // ---- MLP (R4): h in 64-col chunks (dbuf), out^T accumulated in regs ----
    f32x4 oacc[4][4];
    #pragma unroll
    for (int i = 0; i < 4; ++i)
        #pragma unroll
        for (int j = 0; j < 4; ++j) oacc[i][j] = z;

    const int hr = w >> 1;
    const int hj = w & 1;
    #pragma unroll 2
    for (int q = 0; q < 8; ++q) {
        const int buf = RBASE + 8192 * (q & 1);
        f32x4 hacc0 = z, hacc1 = z;
        #pragma unroll
        for (int side = 0; side < 2; ++side) {
            const _Float16* up = UT + (size_t)(64 * q + 32 * hj + c) * HH + side * 256;
            #pragma unroll
            for (int ks = 0; ks < 8; ++ks) {
                half8 afr = *reinterpret_cast<const half8*>(lds + axX(side, 16 * hr + c, 32 * ks + 8 * kg));
                half8 bf0 = ld8(up + 32 * ks + 8 * kg);
                half8 bf1 = ld8(up + 16 * HH + 32 * ks + 8 * kg);
                hacc0 = __builtin_amdgcn_mfma_f32_16x16x32_f16(afr, bf0, hacc0, 0, 0, 0);
                hacc1 = __builtin_amdgcn_mfma_f32_16x16x32_f16(afr, bf1, hacc1, 0, 0, 0);
            }
        }
        const float bb0 = b1[64 * q + 32 * hj + c];
        const float bb1 = b1[64 * q + 32 * hj + 16 + c];
        #pragma unroll
        for (int r = 0; r < 4; ++r) {
            *reinterpret_cast<_Float16*>(lds + axH(buf, 16 * hr + 4 * kg + r, 32 * hj + c)) =
                (_Float16)fmaxf(hacc0[r] + bb0, 0.f);
            *reinterpret_cast<_Float16*>(lds + axH(buf, 16 * hr + 4 * kg + r, 32 * hj + 16 + c)) =
                (_Float16)fmaxf(hacc1[r] + bb1, 0.f);
        }
        __syncthreads();
        __builtin_amdgcn_s_setprio(1);
        #pragma unroll
        for (int ks = 0; ks < 2; ++ks) {
            half8 bfr2[4];
            #pragma unroll
            for (int nj = 0; nj < 4; ++nj)
                bfr2[nj] = *reinterpret_cast<const half8*>(lds + axH(buf, 16 * nj + c, 32 * ks + 8 * kg));
            #pragma unroll
            for (int i = 0; i < 4; ++i) {
                half8 af2 = ld8(W2T + (size_t)(64 * w + 16 * i + c) * HH + 64 * q + 32 * ks + 8 * kg);
                #pragma unroll
                for (int nj = 0; nj < 4; ++nj)
                    oacc[i][nj] = __builtin_amdgcn_mfma_f32_16x16x32_f16(af2, bfr2[nj], oacc[i][nj], 0, 0, 0);
            }
        }
        __builtin_amdgcn_s_setprio(0);
    }

    // ---- Epilogue: out^T regs -> coalesced float4 stores ----
    float* og = out + g * (size_t)(NB * HH);
    #pragma unroll
    for (int i = 0; i < 4; ++i) {
        const int ocol0 = 64 * w + 16 * i + 4 * kg;
        const float4 b2v = *reinterpret_cast<const float4*>(b2 + ocol0);
        #pragma unroll
        for (int nj = 0; nj < 4; ++nj) {
            float4 res;
            res.x = oacc[i][nj][0] + b2v.x;
            res.y = oacc[i][nj][1] + b2v.y;
            res.z = oacc[i][nj][2] + b2v.z;
            res.w = oacc[i][nj][3] + b2v.w;
            *reinterpret_cast<float4*>(og + (size_t)(16 * nj + c) * HH + ocol0) = res;
        }
    }
}

// ---------------- launch ----------------

extern "C" void kernel_launch(void* const* d_in, const int* in_sizes, int n_in,
                              void* d_out, int out_size, void* d_ws, size_t ws_size,
                              hipStream_t stream) {
    (void)in_sizes; (void)n_in; (void)out_size; (void)ws_size;
    const float* x1  = (const float*)d_in[0];
    const float* x2  = (const float*)d_in[1];
    const float* Wq1 = (const float*)d_in[2];
    const float* Wk1 = (const float*)d_in[3];
    const float* Wv1 = (const float*)d_in[4];
    const float* Wq2 = (const float*)d_in[5];
    const float* Wk2 = (const float*)d_in[6];
    const float* Wv2 = (const float*)d_in[7];
    const float* W1  = (const float*)d_in[8];
    const float* b1  = (const float*)d_in[9];
    const float* W2  = (const float*)d_in[10];
    const float* b2  = (const float*)d_in[11];
    float* out = (float*)d_out;

    char* ws = (char*)d_ws;
    _Float16* G1  = (_Float16*)(ws + 0);
    _Float16* G2  = (_Float16*)(ws + 131072);
    _Float16* UT  = (_Float16*)(ws + 262144);   // [512][512] combined
    _Float16* W2T = (_Float16*)(ws + 786432);

    const float scale = 0.0625f;

    prep_G_kernel<<<DD, DD, 0, stream>>>(Wq1, Wk2, G1, scale);
    prep_G_kernel<<<DD, DD, 0, stream>>>(Wq2, Wk1, G2, scale);
    prep_U_kernel<<<HH, DD, 0, stream>>>(Wv1, W1, UT, 0);
    prep_U_kernel<<<HH, DD, 0, stream>>>(Wv2, W1 + HH * HH, UT, 256);
    prep_W2T_kernel<<<dim3(16, 16), 256, 0, stream>>>(W2, W2T);

    fused_kernel<<<NGROUP, 512, 0, stream>>>(x1, x2, G1, G2, UT, W2T, b1, b2, out);
}

// Round 6
// 615.978 us; speedup vs baseline: 1.4862x; 1.4862x over previous
//
#include <hip/hip_runtime.h>
#include <stdint.h>

#define NB 64
#define DD 256
#define HH 512
#define NGROUP 2048

typedef __attribute__((ext_vector_type(8))) _Float16 half8;
typedef __attribute__((ext_vector_type(4))) float f32x4;

__device__ __forceinline__ half8 ld8(const _Float16* p) {
    return *reinterpret_cast<const half8*>(p);
}

// ---------------- precompute kernels (validated R1-R5) ----------------

__global__ void prep_G_kernel(const float* __restrict__ Wq, const float* __restrict__ Wk,
                              _Float16* __restrict__ G, float scale) {
    const int d = blockIdx.x;
    const int e = threadIdx.x;
    const float4* qa = reinterpret_cast<const float4*>(Wq + d * HH);
    const float4* ka = reinterpret_cast<const float4*>(Wk + e * HH);
    float s = 0.f;
    #pragma unroll 8
    for (int j = 0; j < HH / 4; ++j) {
        float4 a = qa[j], b = ka[j];
        s += a.x * b.x + a.y * b.y + a.z * b.z + a.w * b.w;
    }
    G[d * DD + e] = (_Float16)(s * scale);
}

__global__ void prep_U_kernel(const float* __restrict__ Wv, const float* __restrict__ W1p,
                              _Float16* __restrict__ UT, int coff) {
    const int o = blockIdx.x;
    const int d = threadIdx.x;
    const float4* va = reinterpret_cast<const float4*>(Wv + d * HH);
    float s = 0.f;
    #pragma unroll 4
    for (int j4 = 0; j4 < HH / 4; ++j4) {
        float4 a = va[j4];
        const int j = j4 * 4;
        s += a.x * W1p[(j + 0) * HH + o];
        s += a.y * W1p[(j + 1) * HH + o];
        s += a.z * W1p[(j + 2) * HH + o];
        s += a.w * W1p[(j + 3) * HH + o];
    }
    UT[o * HH + coff + d] = (_Float16)s;
}

__global__ void prep_W2T_kernel(const float* __restrict__ W2, _Float16* __restrict__ W2T) {
    __shared__ float tile[32][33];
    const int bk = blockIdx.x * 32;
    const int bh = blockIdx.y * 32;
    const int tx = threadIdx.x & 31, ty = threadIdx.x >> 5;
    #pragma unroll
    for (int i = 0; i < 32; i += 8)
        tile[ty + i][tx] = W2[(bh + ty + i) * HH + bk + tx];
    __syncthreads();
    #pragma unroll
    for (int i = 0; i < 32; i += 8)
        W2T[(bk + ty + i) * HH + bh + tx] = (_Float16)tile[tx][ty + i];
}

// ---------------- main fused kernel ----------------
// 256 threads (4 waves), LDS 80 KiB -> 2 blocks/CU, VGPR cap 256 (no spills).
//   X1 @ 0      [64][256] f16 swz -> becomes g1
//   X2 @ 32768  [64][256] f16 swz -> becomes g2
//   R  @ 65536  16 KiB multiplexed:
//     scores: A-chunk [64][64] dbuf @R / @R+8K
//     PV:     P [64][64] @R, XT [64][64] @R+8K
//     MLP:    h-chunk [64][64] dbuf @R / @R+8K
// swizzle: byte ^= (row&7)<<4

#define RBASE 65536
__device__ __forceinline__ int axX(int side, int row, int ec) {   // 512B rows
    return side * 32768 + row * 512 + ((2 * ec) ^ ((row & 7) << 4));
}
__device__ __forceinline__ int axR8(int base, int row, int ec) {  // 128B rows
    return base + row * 128 + ((2 * ec) ^ ((row & 7) << 4));
}

__global__ __launch_bounds__(256, 2)
void fused_kernel(const float* __restrict__ x1g, const float* __restrict__ x2g,
                  const _Float16* __restrict__ G1, const _Float16* __restrict__ G2,
                  const _Float16* __restrict__ UT, const _Float16* __restrict__ W2T,
                  const float* __restrict__ b1, const float* __restrict__ b2,
                  float* __restrict__ out) {
    __shared__ __align__(16) char lds[81920];

    const int tid = threadIdx.x;
    const int lane = tid & 63;
    const int w = tid >> 6;        // wave 0..3
    const int c = lane & 15;
    const int kg = lane >> 4;
    const size_t g = blockIdx.x;
    const f32x4 z = {0.f, 0.f, 0.f, 0.f};

    // ---- Phase 0: stage x -> f16 swizzled LDS (8 iters, 256 thr) ----
    {
        const float4* s1 = reinterpret_cast<const float4*>(x1g) + g * (NB * DD / 4);
        const float4* s2 = reinterpret_cast<const float4*>(x2g) + g * (NB * DD / 4);
        #pragma unroll
        for (int it = 0; it < 8; ++it) {
            const int G_ = tid + 256 * it;
            const int row = G_ >> 5, cg = G_ & 31;
            float4 a0 = s1[row * 64 + cg * 2], a1 = s1[row * 64 + cg * 2 + 1];
            float4 b0 = s2[row * 64 + cg * 2], b1v = s2[row * 64 + cg * 2 + 1];
            half8 ha, hb;
            ha[0] = (_Float16)a0.x; ha[1] = (_Float16)a0.y; ha[2] = (_Float16)a0.z; ha[3] = (_Float16)a0.w;
            ha[4] = (_Float16)a1.x; ha[5] = (_Float16)a1.y; ha[6] = (_Float16)a1.z; ha[7] = (_Float16)a1.w;
            hb[0] = (_Float16)b0.x; hb[1] = (_Float16)b0.y; hb[2] = (_Float16)b0.z; hb[3] = (_Float16)b0.w;
            hb[4] = (_Float16)b1v.x; hb[5] = (_Float16)b1v.y; hb[6] = (_Float16)b1v.z; hb[7] = (_Float16)b1v.w;
            *reinterpret_cast<half8*>(lds + axX(0, row, cg * 8)) = ha;
            *reinterpret_cast<half8*>(lds + axX(1, row, cg * 8)) = hb;
        }
    }
    __syncthreads();

    // ---- Scores: 64-col A-chunks (dbuf). Every wave holds 16 rows of BOTH S1,S2 ----
    f32x4 S1acc[4] = {z, z, z, z};
    f32x4 S2acc[4] = {z, z, z, z};
    #pragma unroll
    for (int ai = 0; ai < 2; ++ai) {
        const _Float16* Gm = ai ? G2 : G1;
        const int xsrc = ai ? 0 : 1;   // A2 = X2@G1^T ; A1 = X1@G2^T
        const int xq   = ai ? 1 : 0;   // S1 = X1@A2^T ; S2 = X2@A1^T
        #pragma unroll
        for (int ci = 0; ci < 4; ++ci) {
            const int buf = RBASE + 8192 * (ci & 1);
            // A-chunk: cols d' = 64ci + 16w + c, all 64 rows m (per wave: 16 cols)
            const _Float16* gp = Gm + (size_t)(64 * ci + 16 * w + c) * DD;
            half8 bf[8];
            #pragma unroll
            for (int ks = 0; ks < 8; ++ks) bf[ks] = ld8(gp + 32 * ks + 8 * kg);
            #pragma unroll
            for (int i = 0; i < 4; ++i) {
                f32x4 acc = z;
                #pragma unroll
                for (int ks = 0; ks < 8; ++ks) {
                    half8 af = *reinterpret_cast<const half8*>(lds + axX(xsrc, 16 * i + c, 32 * ks + 8 * kg));
                    acc = __builtin_amdgcn_mfma_f32_16x16x32_f16(af, bf[ks], acc, 0, 0, 0);
                }
                #pragma unroll
                for (int r = 0; r < 4; ++r)
                    *reinterpret_cast<_Float16*>(lds + axR8(buf, 16 * i + 4 * kg + r, 16 * w + c)) = (_Float16)acc[r];
            }
            __syncthreads();
            // S partial: rows 16w..16w+15, all 64 m
            f32x4* Sacc = ai ? S2acc : S1acc;
            #pragma unroll
            for (int ks = 0; ks < 2; ++ks) {
                half8 af = *reinterpret_cast<const half8*>(lds + axX(xq, 16 * w + c, 64 * ci + 32 * ks + 8 * kg));
                #pragma unroll
                for (int j = 0; j < 4; ++j) {
                    half8 bfr = *reinterpret_cast<const half8*>(lds + axR8(buf, 16 * j + c, 32 * ks + 8 * kg));
                    Sacc[j] = __builtin_amdgcn_mfma_f32_16x16x32_f16(af, bfr, Sacc[j], 0, 0, 0);
                }
            }
            // no sync: dbuf; next chunk writes the other buffer
        }
    }

    // ---- softmax + PV, per side (P @ R, XT @ R+8K; g overwrites X in-place) ----
    #pragma unroll
    for (int s = 0; s < 2; ++s) {
        // softmax of this side's scores (in regs) -> P f16 @ RBASE
        {
            const f32x4* Sacc = s ? S2acc : S1acc;
            #pragma unroll
            for (int r = 0; r < 4; ++r) {
                float m0 = fmaxf(fmaxf(Sacc[0][r], Sacc[1][r]), fmaxf(Sacc[2][r], Sacc[3][r]));
                m0 = fmaxf(m0, __shfl_xor(m0, 1));
                m0 = fmaxf(m0, __shfl_xor(m0, 2));
                m0 = fmaxf(m0, __shfl_xor(m0, 4));
                m0 = fmaxf(m0, __shfl_xor(m0, 8));
                float e0 = __expf(Sacc[0][r] - m0);
                float e1 = __expf(Sacc[1][r] - m0);
                float e2 = __expf(Sacc[2][r] - m0);
                float e3 = __expf(Sacc[3][r] - m0);
                float s0 = e0 + e1 + e2 + e3;
                s0 += __shfl_xor(s0, 1);
                s0 += __shfl_xor(s0, 2);
                s0 += __shfl_xor(s0, 4);
                s0 += __shfl_xor(s0, 8);
                const float inv = 1.f / s0;
                const int row = 16 * w + 4 * kg + r;
                *reinterpret_cast<_Float16*>(lds + axR8(RBASE, row, 16 * 0 + c)) = (_Float16)(e0 * inv);
                *reinterpret_cast<_Float16*>(lds + axR8(RBASE, row, 16 * 1 + c)) = (_Float16)(e1 * inv);
                *reinterpret_cast<_Float16*>(lds + axR8(RBASE, row, 16 * 2 + c)) = (_Float16)(e2 * inv);
                *reinterpret_cast<_Float16*>(lds + axR8(RBASE, row, 16 * 3 + c)) = (_Float16)(e3 * inv);
            }
        }
        __syncthreads();

        // P A-fragments (rows 16w.., K = m 0..63)
        half8 paf0 = *reinterpret_cast<const half8*>(lds + axR8(RBASE, 16 * w + c, 8 * kg));
        half8 paf1 = *reinterpret_cast<const half8*>(lds + axR8(RBASE, 16 * w + c, 32 + 8 * kg));

        #pragma unroll
        for (int ci = 0; ci < 4; ++ci) {
            // transpose 64-col X slice -> XT[d-local][m] @ R+8K
            const int tm = tid >> 2, tq = tid & 3;
            half8 v0 = *reinterpret_cast<const half8*>(lds + axX(s, tm, 64 * ci + 8 * tq));
            half8 v1 = *reinterpret_cast<const half8*>(lds + axX(s, tm, 64 * ci + 32 + 8 * tq));
            #pragma unroll
            for (int e = 0; e < 8; ++e) {
                *reinterpret_cast<_Float16*>(lds + axR8(RBASE + 8192, 8 * tq + e, tm)) = v0[e];
                *reinterpret_cast<_Float16*>(lds + axR8(RBASE + 8192, 32 + 8 * tq + e, tm)) = v1[e];
            }
            __syncthreads();
            // g chunk [64 rows][64 d]: wave rows 16w..; 4 d-tiles
            f32x4 acc[4] = {z, z, z, z};
            #pragma unroll
            for (int ks = 0; ks < 2; ++ks) {
                half8 pa = ks ? paf1 : paf0;
                #pragma unroll
                for (int dt = 0; dt < 4; ++dt) {
                    half8 bfr = *reinterpret_cast<const half8*>(lds + axR8(RBASE + 8192, 16 * dt + c, 32 * ks + 8 * kg));
                    acc[dt] = __builtin_amdgcn_mfma_f32_16x16x32_f16(pa, bfr, acc[dt], 0, 0, 0);
                }
            }
            // g overwrites the consumed 64-col X slice (swizzle-bijective within 128B)
            #pragma unroll
            for (int dt = 0; dt < 4; ++dt)
                #pragma unroll
                for (int r = 0; r < 4; ++r)
                    *reinterpret_cast<_Float16*>(lds + axX(s, 16 * w + 4 * kg + r, 64 * ci + 16 * dt + c)) = (_Float16)acc[dt][r];
            __syncthreads();   // covers g-writes and XT rewrite
        }
    }

    // ---- MLP: h in 64-col chunks (dbuf @R/R+8K), out^T in oacc[8][4] ----
    f32x4 oacc[8][4];
    #pragma unroll
    for (int i = 0; i < 8; ++i)
        #pragma unroll
        for (int j = 0; j < 4; ++j) oacc[i][j] = z;

    #pragma unroll
    for (int q = 0; q < 8; ++q) {
        const int buf = RBASE + 8192 * (q & 1);
        const int hcol = 64 * q + 16 * w + c;
        f32x4 hacc[4] = {z, z, z, z};
        #pragma unroll
        for (int side = 0; side < 2; ++side) {
            const _Float16* up = UT + (size_t)hcol * HH + side * 256;
            #pragma unroll
            for (int ks = 0; ks < 8; ++ks) {
                half8 bfb = ld8(up + 32 * ks + 8 * kg);
                #pragma unroll
                for (int i = 0; i < 4; ++i) {
                    half8 af = *reinterpret_cast<const half8*>(lds + axX(side, 16 * i + c, 32 * ks + 8 * kg));
                    hacc[i] = __builtin_amdgcn_mfma_f32_16x16x32_f16(af, bfb, hacc[i], 0, 0, 0);
                }
            }
        }
        const float bb = b1[hcol];
        #pragma unroll
        for (int i = 0; i < 4; ++i)
            #pragma unroll
            for (int r = 0; r < 4; ++r)
                *reinterpret_cast<_Float16*>(lds + axR8(buf, 16 * i + 4 * kg + r, 16 * w + c)) =
                    (_Float16)fmaxf(hacc[i][r] + bb, 0.f);
        __syncthreads();
        // out^T partial: wave owns ocols 128w..128w+127 (8 tiles), K = this h chunk
        #pragma unroll
        for (int ks = 0; ks < 2; ++ks) {
            half8 bfr2[4];
            #pragma unroll
            for (int nj = 0; nj < 4; ++nj)
                bfr2[nj] = *reinterpret_cast<const half8*>(lds + axR8(buf, 16 * nj + c, 32 * ks + 8 * kg));
            #pragma unroll
            for (int i = 0; i < 8; ++i) {
                half8 af2 = ld8(W2T + (size_t)(128 * w + 16 * i + c) * HH + 64 * q + 32 * ks + 8 * kg);
                #pragma unroll
                for (int nj = 0; nj < 4; ++nj)
                    oacc[i][nj] = __builtin_amdgcn_mfma_f32_16x16x32_f16(af2, bfr2[nj], oacc[i][nj], 0, 0, 0);
            }
        }
        // no sync: dbuf; next chunk writes the other buffer
    }

    // ---- Epilogue: out^T regs -> float4 stores ----
    float* og = out + g * (size_t)(NB * HH);
    #pragma unroll
    for (int i = 0; i < 8; ++i) {
        const int ocol0 = 128 * w + 16 * i + 4 * kg;
        const float4 b2v = *reinterpret_cast<const float4*>(b2 + ocol0);
        #pragma unroll
        for (int nj = 0; nj < 4; ++nj) {
            float4 res;
            res.x = oacc[i][nj][0] + b2v.x;
            res.y = oacc[i][nj][1] + b2v.y;
            res.z = oacc[i][nj][2] + b2v.z;
            res.w = oacc[i][nj][3] + b2v.w;
            *reinterpret_cast<float4*>(og + (size_t)(16 * nj + c) * HH + ocol0) = res;
        }
    }
}

// ---------------- launch ----------------

extern "C" void kernel_launch(void* const* d_in, const int* in_sizes, int n_in,
                              void* d_out, int out_size, void* d_ws, size_t ws_size,
                              hipStream_t stream) {
    (void)in_sizes; (void)n_in; (void)out_size; (void)ws_size;
    const float* x1  = (const float*)d_in[0];
    const float* x2  = (const float*)d_in[1];
    const float* Wq1 = (const float*)d_in[2];
    const float* Wk1 = (const float*)d_in[3];
    const float* Wv1 = (const float*)d_in[4];
    const float* Wq2 = (const float*)d_in[5];
    const float* Wk2 = (const float*)d_in[6];
    const float* Wv2 = (const float*)d_in[7];
    const float* W1  = (const float*)d_in[8];
    const float* b1  = (const float*)d_in[9];
    const float* W2  = (const float*)d_in[10];
    const float* b2  = (const float*)d_in[11];
    float* out = (float*)d_out;

    char* ws = (char*)d_ws;
    _Float16* G1  = (_Float16*)(ws + 0);
    _Float16* G2  = (_Float16*)(ws + 131072);
    _Float16* UT  = (_Float16*)(ws + 262144);   // [512][512] combined
    _Float16* W2T = (_Float16*)(ws + 786432);

    const float scale = 0.0625f;

    prep_G_kernel<<<DD, DD, 0, stream>>>(Wq1, Wk2, G1, scale);
    prep_G_kernel<<<DD, DD, 0, stream>>>(Wq2, Wk1, G2, scale);
    prep_U_kernel<<<HH, DD, 0, stream>>>(Wv1, W1, UT, 0);
    prep_U_kernel<<<HH, DD, 0, stream>>>(Wv2, W1 + HH * HH, UT, 256);
    prep_W2T_kernel<<<dim3(16, 16), 256, 0, stream>>>(W2, W2T);

    fused_kernel<<<NGROUP, 256, 0, stream>>>(x1, x2, G1, G2, UT, W2T, b1, b2, out);
}

// Round 7
// 568.401 us; speedup vs baseline: 1.6106x; 1.0837x over previous
//
#include <hip/hip_runtime.h>
#include <stdint.h>

#define NB 64
#define DD 256
#define HH 512
#define NGROUP 2048

typedef __attribute__((ext_vector_type(8))) _Float16 half8;
typedef __attribute__((ext_vector_type(4))) _Float16 half4;
typedef __attribute__((ext_vector_type(4))) float f32x4;

__device__ __forceinline__ half8 ld8(const _Float16* p) {
    return *reinterpret_cast<const half8*>(p);
}

// ---------------- merged prep kernel (G1,G2,UT,W2T in one launch) ----------------
// grid 1792 x 256:
//   b in [0,256)    : G1[d][e] = scale * Wq1[d,:]. Wk2[e,:]
//   b in [256,512)  : G2[d][e] = scale * Wq2[d,:] . Wk1[e,:]
//   b in [512,1024) : UT[o][d]      = Wv1[d,:] . W1[:,o]        (o = b-512)
//   b in [1024,1536): UT[o][256+d]  = Wv2[d,:] . W1[512+:,o]
//   b in [1536,1792): W2T tile transpose
__global__ void prep_all(const float* __restrict__ Wq1, const float* __restrict__ Wk1,
                         const float* __restrict__ Wv1, const float* __restrict__ Wq2,
                         const float* __restrict__ Wk2, const float* __restrict__ Wv2,
                         const float* __restrict__ W1, const float* __restrict__ W2,
                         _Float16* __restrict__ G1, _Float16* __restrict__ G2,
                         _Float16* __restrict__ UT, _Float16* __restrict__ W2T,
                         float scale) {
    const int b = blockIdx.x, t = threadIdx.x;
    if (b < 512) {
        const float* A = (b < 256) ? Wq1 : Wq2;
        const float* Bm = (b < 256) ? Wk2 : Wk1;
        _Float16* G = (b < 256) ? G1 : G2;
        const int d = b & 255, e = t;
        const float4* qa = reinterpret_cast<const float4*>(A + d * HH);
        const float4* ka = reinterpret_cast<const float4*>(Bm + e * HH);
        float s = 0.f;
        #pragma unroll 8
        for (int j = 0; j < HH / 4; ++j) {
            float4 a = qa[j], bb = ka[j];
            s += a.x * bb.x + a.y * bb.y + a.z * bb.z + a.w * bb.w;
        }
        G[d * DD + e] = (_Float16)(s * scale);
    } else if (b < 1536) {
        const int half = (b - 512) >> 9;        // 0 or 1
        const int o = (b - 512) & 511;
        const float* Wv = half ? Wv2 : Wv1;
        const float* W1p = W1 + half * HH * HH;
        const int d = t;
        const float4* va = reinterpret_cast<const float4*>(Wv + d * HH);
        float s = 0.f;
        #pragma unroll 4
        for (int j4 = 0; j4 < HH / 4; ++j4) {
            float4 a = va[j4];
            const int j = j4 * 4;
            s += a.x * W1p[(j + 0) * HH + o];
            s += a.y * W1p[(j + 1) * HH + o];
            s += a.z * W1p[(j + 2) * HH + o];
            s += a.w * W1p[(j + 3) * HH + o];
        }
        UT[o * HH + half * 256 + d] = (_Float16)s;
    } else {
        __shared__ float tile[32][33];
        const int bi = b - 1536;
        const int bk = (bi & 15) * 32;
        const int bh = (bi >> 4) * 32;
        const int tx = t & 31, ty = t >> 5;
        #pragma unroll
        for (int i = 0; i < 32; i += 8)
            tile[ty + i][tx] = W2[(bh + ty + i) * HH + bk + tx];
        __syncthreads();
        #pragma unroll
        for (int i = 0; i < 32; i += 8)
            W2T[(bk + ty + i) * HH + bh + tx] = (_Float16)tile[tx][ty + i];
    }
}

// ---------------- main fused kernel ----------------
// 512 threads (8 waves), 160 KiB LDS, 1 block/CU, VGPR cap 256 (launch_bounds(512,2)).
// LDS map:
//   X1  @ 0      [64][256] f16 swz -> becomes g1
//   X2  @ 32768  [64][256] f16 swz -> becomes g2
//   XT1 @ 65536  [256][64] f16 swz (X1^T, built once at stage)
//   XT2 @ 98304  [256][64] f16 swz
//   R   @ 131072 32 KiB multiplexed:
//     scores: A-chunk dbuf, each buf = {side0 [64][64], side1 [64][64]} (16K x2)
//     P1 @ R, P2 @ R+8K (after scores)
//     MLP: h-chunk [64][128] dbuf @R / @R+16K
// swizzle everywhere: byte ^= (row&7)<<4

#define LDS_XT 65536
#define LDS_R  131072

__device__ __forceinline__ int axX(int side, int row, int ec) {   // 512B rows
    return side * 32768 + row * 512 + ((2 * ec) ^ ((row & 7) << 4));
}
__device__ __forceinline__ int axXT(int side, int row, int ec) {  // 128B rows, 256 rows
    return LDS_XT + side * 32768 + row * 128 + ((2 * ec) ^ ((row & 7) << 4));
}
__device__ __forceinline__ int axA(int buf, int side, int row, int ec) {  // 128B rows
    return LDS_R + buf * 16384 + side * 8192 + row * 128 + ((2 * ec) ^ ((row & 7) << 4));
}
__device__ __forceinline__ int axP(int side, int row, int ec) {   // 128B rows
    return LDS_R + side * 8192 + row * 128 + ((2 * ec) ^ ((row & 7) << 4));
}
__device__ __forceinline__ int axH(int buf, int row, int ec) {    // 256B rows ([64][128])
    return LDS_R + buf * 16384 + row * 256 + ((2 * ec) ^ ((row & 7) << 4));
}

__global__ __launch_bounds__(512, 2)
void fused_kernel(const float* __restrict__ x1g, const float* __restrict__ x2g,
                  const _Float16* __restrict__ G1, const _Float16* __restrict__ G2,
                  const _Float16* __restrict__ UT, const _Float16* __restrict__ W2T,
                  const float* __restrict__ b1, const float* __restrict__ b2,
                  float* __restrict__ out) {
    __shared__ __align__(16) char lds[163840];

    const int tid = threadIdx.x;
    const int lane = tid & 63;
    const int w = tid >> 6;        // wave 0..7
    const int c = lane & 15;
    const int kg = lane >> 4;
    const int s = w >> 2;          // side this wave owns (0: S1/P1/g1, 1: S2/P2/g2)
    const int wa = w & 3;          // row-tile within side
    const size_t g = blockIdx.x;
    const f32x4 z = {0.f, 0.f, 0.f, 0.f};

    // ---- Phase 0a: stage x -> X f16 (coalesced 1KB/instr reads, b64 LDS writes) ----
    {
        const float* xs0 = x1g + g * (NB * DD);
        const float* xs1 = x2g + g * (NB * DD);
        #pragma unroll
        for (int it = 0; it < 8; ++it) {
            const int row = 8 * w + it;
            float4 a = reinterpret_cast<const float4*>(xs0 + row * DD)[lane];
            float4 b = reinterpret_cast<const float4*>(xs1 + row * DD)[lane];
            half4 ha, hb;
            ha[0] = (_Float16)a.x; ha[1] = (_Float16)a.y; ha[2] = (_Float16)a.z; ha[3] = (_Float16)a.w;
            hb[0] = (_Float16)b.x; hb[1] = (_Float16)b.y; hb[2] = (_Float16)b.z; hb[3] = (_Float16)b.w;
            *reinterpret_cast<half4*>(lds + axX(0, row, 4 * lane)) = ha;
            *reinterpret_cast<half4*>(lds + axX(1, row, 4 * lane)) = hb;
        }
    }
    __syncthreads();

    // ---- Phase 0b: build XT once (wave-uniform-row writes: conflict-free) ----
    {
        #pragma unroll
        for (int jj = 0; jj < 8; ++jj) {
            half8 v = *reinterpret_cast<const half8*>(lds + axX(s, lane, 64 * wa + 8 * jj));
            #pragma unroll
            for (int e = 0; e < 8; ++e)
                *reinterpret_cast<_Float16*>(lds + axXT(s, 64 * wa + 8 * jj + e, lane)) = v[e];
        }
    }
    __syncthreads();

    // ---- Scores: 4 dbuf chunk-rounds; wave computes its side's A cols + S rows ----
    // side 0: A2 = X2@G1^T, S1 = X1@A2^T ; side 1: A1 = X1@G2^T, S2 = X2@A1^T
    f32x4 Sacc[4] = {z, z, z, z};
    {
        const _Float16* Gsel = s ? G2 : G1;
        const int xo = 1 - s;    // A-source X side
        #pragma unroll
        for (int ci = 0; ci < 4; ++ci) {
            const int buf = ci & 1;
            const int dcol = 64 * ci + 16 * wa + c;
            const _Float16* gp = Gsel + (size_t)dcol * DD;
            half8 bf[8];
            #pragma unroll
            for (int ks = 0; ks < 8; ++ks) bf[ks] = ld8(gp + 32 * ks + 8 * kg);
            #pragma unroll
            for (int i = 0; i < 4; ++i) {
                f32x4 acc = z;
                #pragma unroll
                for (int ks = 0; ks < 8; ++ks) {
                    half8 af = *reinterpret_cast<const half8*>(lds + axX(xo, 16 * i + c, 32 * ks + 8 * kg));
                    acc = __builtin_amdgcn_mfma_f32_16x16x32_f16(af, bf[ks], acc, 0, 0, 0);
                }
                #pragma unroll
                for (int r = 0; r < 4; ++r)
                    *reinterpret_cast<_Float16*>(lds + axA(buf, s, 16 * i + 4 * kg + r, 16 * wa + c)) = (_Float16)acc[r];
            }
            __syncthreads();
            #pragma unroll
            for (int ks = 0; ks < 2; ++ks) {
                half8 af = *reinterpret_cast<const half8*>(lds + axX(s, 16 * wa + c, 64 * ci + 32 * ks + 8 * kg));
                #pragma unroll
                for (int j = 0; j < 4; ++j) {
                    half8 bfr = *reinterpret_cast<const half8*>(lds + axA(buf, s, 16 * j + c, 32 * ks + 8 * kg));
                    Sacc[j] = __builtin_amdgcn_mfma_f32_16x16x32_f16(af, bfr, Sacc[j], 0, 0, 0);
                }
            }
        }
    }

    // ---- Softmax (rows 16wa.., in regs) -> P[s] @ R ----
    {
        #pragma unroll
        for (int r = 0; r < 4; ++r) {
            float m0 = fmaxf(fmaxf(Sacc[0][r], Sacc[1][r]), fmaxf(Sacc[2][r], Sacc[3][r]));
            m0 = fmaxf(m0, __shfl_xor(m0, 1));
            m0 = fmaxf(m0, __shfl_xor(m0, 2));
            m0 = fmaxf(m0, __shfl_xor(m0, 4));
            m0 = fmaxf(m0, __shfl_xor(m0, 8));
            float e0 = __expf(Sacc[0][r] - m0);
            float e1 = __expf(Sacc[1][r] - m0);
            float e2 = __expf(Sacc[2][r] - m0);
            float e3 = __expf(Sacc[3][r] - m0);
            float s0 = e0 + e1 + e2 + e3;
            s0 += __shfl_xor(s0, 1);
            s0 += __shfl_xor(s0, 2);
            s0 += __shfl_xor(s0, 4);
            s0 += __shfl_xor(s0, 8);
            const float inv = 1.f / s0;
            const int row = 16 * wa + 4 * kg + r;
            *reinterpret_cast<_Float16*>(lds + axP(s, row, 16 * 0 + c)) = (_Float16)(e0 * inv);
            *reinterpret_cast<_Float16*>(lds + axP(s, row, 16 * 1 + c)) = (_Float16)(e1 * inv);
            *reinterpret_cast<_Float16*>(lds + axP(s, row, 16 * 2 + c)) = (_Float16)(e2 * inv);
            *reinterpret_cast<_Float16*>(lds + axP(s, row, 16 * 3 + c)) = (_Float16)(e3 * inv);
        }
    }
    __syncthreads();

    // ---- PV: g[s] rows 16wa = P[s] @ X[s] via XT (no transposes, 32 MFMA) ----
    {
        half8 paf0 = *reinterpret_cast<const half8*>(lds + axP(s, 16 * wa + c, 8 * kg));
        half8 paf1 = *reinterpret_cast<const half8*>(lds + axP(s, 16 * wa + c, 32 + 8 * kg));
        #pragma unroll
        for (int dt = 0; dt < 16; ++dt) {
            f32x4 acc = z;
            half8 b0 = *reinterpret_cast<const half8*>(lds + axXT(s, 16 * dt + c, 8 * kg));
            half8 b1v = *reinterpret_cast<const half8*>(lds + axXT(s, 16 * dt + c, 32 + 8 * kg));
            acc = __builtin_amdgcn_mfma_f32_16x16x32_f16(paf0, b0, acc, 0, 0, 0);
            acc = __builtin_amdgcn_mfma_f32_16x16x32_f16(paf1, b1v, acc, 0, 0, 0);
            #pragma unroll
            for (int r = 0; r < 4; ++r)
                *reinterpret_cast<_Float16*>(lds + axX(s, 16 * wa + 4 * kg + r, 16 * dt + c)) = (_Float16)acc[r];
        }
    }
    __syncthreads();

    // ---- MLP: 4 dbuf chunk-rounds; h [64][128] per chunk; out^T in oacc[4][4] ----
    f32x4 oacc[4][4];
    #pragma unroll
    for (int i = 0; i < 4; ++i)
        #pragma unroll
        for (int j = 0; j < 4; ++j) oacc[i][j] = z;

    #pragma unroll
    for (int q = 0; q < 4; ++q) {
        const int buf = q & 1;
        const int hcol = 128 * q + 16 * w + c;
        f32x4 hacc[4] = {z, z, z, z};
        #pragma unroll
        for (int side = 0; side < 2; ++side) {
            const _Float16* up = UT + (size_t)hcol * HH + side * 256;
            #pragma unroll
            for (int ks = 0; ks < 8; ++ks) {
                half8 bfb = ld8(up + 32 * ks + 8 * kg);
                #pragma unroll
                for (int i = 0; i < 4; ++i) {
                    half8 af = *reinterpret_cast<const half8*>(lds + axX(side, 16 * i + c, 32 * ks + 8 * kg));
                    hacc[i] = __builtin_amdgcn_mfma_f32_16x16x32_f16(af, bfb, hacc[i], 0, 0, 0);
                }
            }
        }
        const float bb = b1[hcol];
        #pragma unroll
        for (int i = 0; i < 4; ++i)
            #pragma unroll
            for (int r = 0; r < 4; ++r)
                *reinterpret_cast<_Float16*>(lds + axH(buf, 16 * i + 4 * kg + r, 16 * w + c)) =
                    (_Float16)fmaxf(hacc[i][r] + bb, 0.f);
        __syncthreads();
        __builtin_amdgcn_s_setprio(1);
        #pragma unroll
        for (int ks = 0; ks < 4; ++ks) {
            half8 bfr2[4];
            #pragma unroll
            for (int nj = 0; nj < 4; ++nj)
                bfr2[nj] = *reinterpret_cast<const half8*>(lds + axH(buf, 16 * nj + c, 32 * ks + 8 * kg));
            #pragma unroll
            for (int i = 0; i < 4; ++i) {
                half8 af2 = ld8(W2T + (size_t)(64 * w + 16 * i + c) * HH + 128 * q + 32 * ks + 8 * kg);
                #pragma unroll
                for (int nj = 0; nj < 4; ++nj)
                    oacc[i][nj] = __builtin_amdgcn_mfma_f32_16x16x32_f16(af2, bfr2[nj], oacc[i][nj], 0, 0, 0);
            }
        }
        __builtin_amdgcn_s_setprio(0);
    }

    // ---- Epilogue: out^T regs (reg r = consecutive ocol) -> float4 stores ----
    float* og = out + g * (size_t)(NB * HH);
    #pragma unroll
    for (int i = 0; i < 4; ++i) {
        const int ocol0 = 64 * w + 16 * i + 4 * kg;
        const float4 b2v = *reinterpret_cast<const float4*>(b2 + ocol0);
        #pragma unroll
        for (int nj = 0; nj < 4; ++nj) {
            float4 res;
            res.x = oacc[i][nj][0] + b2v.x;
            res.y = oacc[i][nj][1] + b2v.y;
            res.z = oacc[i][nj][2] + b2v.z;
            res.w = oacc[i][nj][3] + b2v.w;
            *reinterpret_cast<float4*>(og + (size_t)(16 * nj + c) * HH + ocol0) = res;
        }
    }
}

// ---------------- launch ----------------

extern "C" void kernel_launch(void* const* d_in, const int* in_sizes, int n_in,
                              void* d_out, int out_size, void* d_ws, size_t ws_size,
                              hipStream_t stream) {
    (void)in_sizes; (void)n_in; (void)out_size; (void)ws_size;
    const float* x1  = (const float*)d_in[0];
    const float* x2  = (const float*)d_in[1];
    const float* Wq1 = (const float*)d_in[2];
    const float* Wk1 = (const float*)d_in[3];
    const float* Wv1 = (const float*)d_in[4];
    const float* Wq2 = (const float*)d_in[5];
    const float* Wk2 = (const float*)d_in[6];
    const float* Wv2 = (const float*)d_in[7];
    const float* W1  = (const float*)d_in[8];
    const float* b1  = (const float*)d_in[9];
    const float* W2  = (const float*)d_in[10];
    const float* b2  = (const float*)d_in[11];
    float* out = (float*)d_out;

    char* ws = (char*)d_ws;
    _Float16* G1  = (_Float16*)(ws + 0);        // 131072
    _Float16* G2  = (_Float16*)(ws + 131072);   // 131072
    _Float16* UT  = (_Float16*)(ws + 262144);   // 524288 ([512][512] combined)
    _Float16* W2T = (_Float16*)(ws + 786432);   // 524288

    const float scale = 0.0625f;  // D^-0.5

    prep_all<<<1792, 256, 0, stream>>>(Wq1, Wk1, Wv1, Wq2, Wk2, Wv2, W1, W2,
                                       G1, G2, UT, W2T, scale);
    fused_kernel<<<NGROUP, 512, 0, stream>>>(x1, x2, G1, G2, UT, W2T, b1, b2, out);
}